// Round 8
// baseline (102.098 us; speedup 1.0000x reference)
//
#include <hip/hip_runtime.h>

#define T_DIM 256
#define B_DIM 8
#define DIN   256
#define DM    256
#define A_DIM 128
#define AP_DIM (A_DIM / 2)   // a-pairs
#define NEG_INF_F (-1e30f)
// tanh(x) needs exp(2x); v_exp_f32 computes 2^y -> projections scaled by 2*log2(e),
// stored as exp2 factors (exp2(ip+mp) = exp2(ip)*exp2(mp)).
#define PRESCALE 2.885390081777927f
#define PROJ_TT 4   // (t,b) rows per proj block
#define S_PAIR  2   // s rows per fused-attention block

// ---------------- Kernel A: projections -> EIP=exp2(ip) [row][a],
//                  EM2=exp2(mp) packed as [b][a/2][t][2] ----------------
__global__ __launch_bounds__(256) void proj_kernel(
    const float* __restrict__ input, const float* __restrict__ memory,
    const float* __restrict__ Wi, const float* __restrict__ Wm,
    float* __restrict__ EIP, float* __restrict__ EM2)
{
    __shared__ float xin[PROJ_TT][DIN];
    __shared__ float xmem[PROJ_TT][DM];
    const int row0 = blockIdx.x * PROJ_TT;           // flat (t*B+b) row index
    const int tid  = threadIdx.x;

    #pragma unroll
    for (int r = 0; r < PROJ_TT; ++r) {
        xin[r][tid]  = input[(row0 + r) * DIN + tid];
        xmem[r][tid] = memory[(row0 + r) * DM + tid];
    }
    __syncthreads();

    if (tid < A_DIM) {
        const int a = tid;
        float acc[PROJ_TT] = {0.f, 0.f, 0.f, 0.f};
        #pragma unroll 8
        for (int d = 0; d < DIN; ++d) {
            const float w = Wi[d * A_DIM + a];
            #pragma unroll
            for (int r = 0; r < PROJ_TT; ++r)
                acc[r] = fmaf(xin[r][d], w, acc[r]);
        }
        #pragma unroll
        for (int r = 0; r < PROJ_TT; ++r)
            EIP[(row0 + r) * A_DIM + a] =
                __builtin_amdgcn_exp2f(acc[r] * PRESCALE);
    } else {
        const int a = tid - A_DIM;
        float acc[PROJ_TT] = {0.f, 0.f, 0.f, 0.f};
        #pragma unroll 8
        for (int d = 0; d < DM; ++d) {
            const float w = Wm[d * A_DIM + a];
            #pragma unroll
            for (int r = 0; r < PROJ_TT; ++r)
                acc[r] = fmaf(xmem[r][d], w, acc[r]);
        }
        #pragma unroll
        for (int r = 0; r < PROJ_TT; ++r) {
            const int t = (row0 + r) / B_DIM, b = (row0 + r) % B_DIM;
            EM2[(((size_t)b * AP_DIM + (a >> 1)) * T_DIM + t) * 2 + (a & 1)] =
                __builtin_amdgcn_exp2f(acc[r] * PRESCALE);
        }
    }
}

__device__ inline float warp_red_max(float v) {
    #pragma unroll
    for (int o = 32; o > 0; o >>= 1) v = fmaxf(v, __shfl_xor(v, o, 64));
    return v;
}
__device__ inline float warp_red_sum(float v) {
    #pragma unroll
    for (int o = 32; o > 0; o >>= 1) v += __shfl_xor(v, o, 64);
    return v;
}

// ---------------- Kernel B: fused logits + softmax + context + concat ----------------
// block per (s-pair, b): 1024 blocks x 4 waves.
// Phase 1 inner loop, paired-rcp form: per a-pair and s-row,
//   v_a/(1+e_a)+v_b/(1+e_b) = [v_a e_b + v_b e_a + (v_a+v_b)] / [(1+e_a)(1+e_b)]
// -> 1 rcp per 2 items; one float2 EM load + one b128 EIP read feed 4 items.
__global__ __launch_bounds__(256) void attn_kernel(
    const float* __restrict__ input, const int* __restrict__ mask,
    const float* __restrict__ v, const float* __restrict__ EIP,
    const float* __restrict__ EM2, float* __restrict__ out)
{
    __shared__ float4 eipv[AP_DIM];   // {e_s0a, e_s0b, e_s1a, e_s1b}
    __shared__ float4 v4[AP_DIM];     // {va, vb, va+vb, 0}
    __shared__ float sc[S_PAIR][T_DIM];
    __shared__ float redm[S_PAIR][4];

    const int blk = blockIdx.x;
    const int b   = blk % B_DIM;          // same-b neighbors -> L2 locality for EM/input
    const int s0  = (blk / B_DIM) * S_PAIR;
    const int tid = threadIdx.x;
    const int lane = tid & 63;
    const int wave = tid >> 6;

    {
        float* eipf = (float*)eipv;
        float* v4f  = (float*)v4;
        if (tid < A_DIM) {
            const int a = tid, ap = a >> 1, j = a & 1;
            eipf[ap * 4 + j]     = EIP[((s0 + 0) * B_DIM + b) * A_DIM + a];
            eipf[ap * 4 + 2 + j] = EIP[((s0 + 1) * B_DIM + b) * A_DIM + a];
            v4f[ap * 4 + j]      = v[a];
        }
        if (tid < AP_DIM) {
            v4f[tid * 4 + 2] = v[2 * tid] + v[2 * tid + 1];
            v4f[tid * 4 + 3] = 0.f;
        }
    }
    __syncthreads();

    // ---- Phase 1: logits. thread = key t. ----
    const int t = tid;
    float acc0 = 0.f, acc1 = 0.f;
    const float2* em_p = (const float2*)EM2 + (size_t)b * AP_DIM * T_DIM + t;
    #pragma unroll 8
    for (int ap = 0; ap < AP_DIM; ++ap) {
        const float2 em = em_p[(size_t)ap * T_DIM];   // coalesced across t
        const float4 ei = eipv[ap];
        const float4 vv = v4[ap];
        // s-row 0
        float ea  = ei.x * em.x;
        float eb  = ei.y * em.y;
        float den = fmaf(ea, eb, (ea + eb) + 1.f);
        float num = fmaf(vv.x, eb, fmaf(vv.y, ea, vv.z));
        acc0 = fmaf(num, __builtin_amdgcn_rcpf(den), acc0);
        // s-row 1
        ea  = ei.z * em.x;
        eb  = ei.w * em.y;
        den = fmaf(ea, eb, (ea + eb) + 1.f);
        num = fmaf(vv.x, eb, fmaf(vv.y, ea, vv.z));
        acc1 = fmaf(num, __builtin_amdgcn_rcpf(den), acc1);
    }

    // v.tanh sum = sumV - 2*acc; constant sumV cancels in softmax.
    const bool valid = (mask[t * B_DIM + b] != 0);
    const float l0 = valid ? (-2.f * acc0) : NEG_INF_F;
    const float l1 = valid ? (-2.f * acc1) : NEG_INF_F;

    // ---- softmax over t, both s rows fused ----
    float m0 = warp_red_max(l0), m1 = warp_red_max(l1);
    if (lane == 0) { redm[0][wave] = m0; redm[1][wave] = m1; }
    __syncthreads();
    m0 = fmaxf(fmaxf(redm[0][0], redm[0][1]), fmaxf(redm[0][2], redm[0][3]));
    m1 = fmaxf(fmaxf(redm[1][0], redm[1][1]), fmaxf(redm[1][2], redm[1][3]));
    const float e0 = __expf(l0 - m0);
    const float e1 = __expf(l1 - m1);
    float su0 = warp_red_sum(e0), su1 = warp_red_sum(e1);
    __syncthreads();
    if (lane == 0) { redm[0][wave] = su0; redm[1][wave] = su1; }
    __syncthreads();
    su0 = (redm[0][0] + redm[0][1]) + (redm[0][2] + redm[0][3]);
    su1 = (redm[1][0] + redm[1][1]) + (redm[1][2] + redm[1][3]);
    sc[0][t] = e0 * __builtin_amdgcn_rcpf(su0);
    sc[1][t] = e1 * __builtin_amdgcn_rcpf(su1);
    __syncthreads();

    // ---- Phase 2: context. thread = feature d. ----
    const int d = tid;
    float c0 = 0.f, c1 = 0.f;
    const float* in_b = input + b * DIN + d;
    #pragma unroll 8
    for (int t2 = 0; t2 < T_DIM; ++t2) {
        const float xv = in_b[(size_t)t2 * B_DIM * DIN];  // coalesced across d
        c0 = fmaf(sc[0][t2], xv, c0);
        c1 = fmaf(sc[1][t2], xv, c1);
    }

    {
        const int r0 = (s0 + 0) * B_DIM + b;
        const int r1 = (s0 + 1) * B_DIM + b;
        out[(size_t)r0 * (2 * DIN) + d]       = c0;
        out[(size_t)r0 * (2 * DIN) + DIN + d] = input[r0 * DIN + d];
        out[(size_t)r1 * (2 * DIN) + d]       = c1;
        out[(size_t)r1 * (2 * DIN) + DIN + d] = input[r1 * DIN + d];
    }
}

extern "C" void kernel_launch(void* const* d_in, const int* in_sizes, int n_in,
                              void* d_out, int out_size, void* d_ws, size_t ws_size,
                              hipStream_t stream) {
    const float* input  = (const float*)d_in[0];
    const float* memory = (const float*)d_in[1];
    const int*   mask   = (const int*)d_in[2];
    const float* Wi     = (const float*)d_in[3];
    const float* Wm     = (const float*)d_in[4];
    const float* v      = (const float*)d_in[5];
    float* out = (float*)d_out;

    float* EIP = (float*)d_ws;                           // [T*B][A]        1 MB  exp2(ip)
    float* EM2 = EIP + (size_t)T_DIM * B_DIM * A_DIM;    // [B][A/2][T][2]  1 MB  exp2(mp) a-paired

    proj_kernel<<<(T_DIM * B_DIM) / PROJ_TT, 256, 0, stream>>>(input, memory, Wi, Wm, EIP, EM2);
    attn_kernel<<<(T_DIM / S_PAIR) * B_DIM, 256, 0, stream>>>(input, mask, v, EIP, EM2, out);
}

// Round 9
// 99.677 us; speedup vs baseline: 1.0243x; 1.0243x over previous
//
#include <hip/hip_runtime.h>

#define T_DIM 256
#define B_DIM 8
#define DIN   256
#define DM    256
#define A_DIM 128
#define AP_DIM (A_DIM / 2)   // a-pairs
#define NEG_INF_F (-1e30f)
// tanh(x) needs exp(2x); v_exp_f32 computes 2^y -> projections scaled by 2*log2(e),
// stored as exp2 factors (exp2(ip+mp) = exp2(ip)*exp2(mp)).
#define PRESCALE 2.885390081777927f
#define PROJ_TT 4   // (t,b) rows per proj block
#define S_PAIR  2   // s rows per fused-attention block

// ---------------- Kernel A: projections -> EIP=exp2(ip) [row][a],
//                  EM2=exp2(mp) packed as [b][a/2][t][2] ----------------
__global__ __launch_bounds__(256) void proj_kernel(
    const float* __restrict__ input, const float* __restrict__ memory,
    const float* __restrict__ Wi, const float* __restrict__ Wm,
    float* __restrict__ EIP, float* __restrict__ EM2)
{
    __shared__ float xin[PROJ_TT][DIN];
    __shared__ float xmem[PROJ_TT][DM];
    const int row0 = blockIdx.x * PROJ_TT;           // flat (t*B+b) row index
    const int tid  = threadIdx.x;

    #pragma unroll
    for (int r = 0; r < PROJ_TT; ++r) {
        xin[r][tid]  = input[(row0 + r) * DIN + tid];
        xmem[r][tid] = memory[(row0 + r) * DM + tid];
    }
    __syncthreads();

    if (tid < A_DIM) {
        const int a = tid;
        float acc[PROJ_TT] = {0.f, 0.f, 0.f, 0.f};
        #pragma unroll 8
        for (int d = 0; d < DIN; ++d) {
            const float w = Wi[d * A_DIM + a];
            #pragma unroll
            for (int r = 0; r < PROJ_TT; ++r)
                acc[r] = fmaf(xin[r][d], w, acc[r]);
        }
        #pragma unroll
        for (int r = 0; r < PROJ_TT; ++r)
            EIP[(row0 + r) * A_DIM + a] =
                __builtin_amdgcn_exp2f(acc[r] * PRESCALE);
    } else {
        const int a = tid - A_DIM;
        float acc[PROJ_TT] = {0.f, 0.f, 0.f, 0.f};
        #pragma unroll 8
        for (int d = 0; d < DM; ++d) {
            const float w = Wm[d * A_DIM + a];
            #pragma unroll
            for (int r = 0; r < PROJ_TT; ++r)
                acc[r] = fmaf(xmem[r][d], w, acc[r]);
        }
        #pragma unroll
        for (int r = 0; r < PROJ_TT; ++r) {
            const int t = (row0 + r) / B_DIM, b = (row0 + r) % B_DIM;
            EM2[(((size_t)b * AP_DIM + (a >> 1)) * T_DIM + t) * 2 + (a & 1)] =
                __builtin_amdgcn_exp2f(acc[r] * PRESCALE);
        }
    }
}

__device__ inline float warp_red_max(float v) {
    #pragma unroll
    for (int o = 32; o > 0; o >>= 1) v = fmaxf(v, __shfl_xor(v, o, 64));
    return v;
}
__device__ inline float warp_red_sum(float v) {
    #pragma unroll
    for (int o = 32; o > 0; o >>= 1) v += __shfl_xor(v, o, 64);
    return v;
}

// ---------------- Kernel B: fused logits + softmax + context + concat ----------------
// block per (s-pair, b): 1024 blocks x 4 waves.
// Phase 1: thread = key t, paired-rcp logits.
// Phase 2: thread = (t-quarter, float4 d-column); 4-way LDS reduction.
__global__ __launch_bounds__(256) void attn_kernel(
    const float* __restrict__ input, const int* __restrict__ mask,
    const float* __restrict__ v, const float* __restrict__ EIP,
    const float* __restrict__ EM2, float* __restrict__ out)
{
    __shared__ float4 eipv[AP_DIM];   // {e_s0a, e_s0b, e_s1a, e_s1b}
    __shared__ float4 v4[AP_DIM];     // {va, vb, va+vb, 0}
    __shared__ float sc[S_PAIR][T_DIM];
    __shared__ float redm[S_PAIR][4];
    __shared__ float4 part[4][S_PAIR][64];   // phase-2 partials, 8 KB

    const int blk = blockIdx.x;
    const int b   = blk % B_DIM;          // same-b neighbors -> L2 locality for EM/input
    const int s0  = (blk / B_DIM) * S_PAIR;
    const int tid = threadIdx.x;
    const int lane = tid & 63;
    const int wave = tid >> 6;

    {
        float* eipf = (float*)eipv;
        float* v4f  = (float*)v4;
        if (tid < A_DIM) {
            const int a = tid, ap = a >> 1, j = a & 1;
            eipf[ap * 4 + j]     = EIP[((s0 + 0) * B_DIM + b) * A_DIM + a];
            eipf[ap * 4 + 2 + j] = EIP[((s0 + 1) * B_DIM + b) * A_DIM + a];
            v4f[ap * 4 + j]      = v[a];
        }
        if (tid < AP_DIM) {
            v4f[tid * 4 + 2] = v[2 * tid] + v[2 * tid + 1];
            v4f[tid * 4 + 3] = 0.f;
        }
    }
    __syncthreads();

    // ---- Phase 1: logits. thread = key t. Paired-rcp:
    //   v_a/(1+e_a)+v_b/(1+e_b) = [v_a e_b + v_b e_a + (v_a+v_b)] / [(1+e_a)(1+e_b)]
    const int t = tid;
    float acc0 = 0.f, acc1 = 0.f;
    const float2* em_p = (const float2*)EM2 + (size_t)b * AP_DIM * T_DIM + t;
    #pragma unroll 8
    for (int ap = 0; ap < AP_DIM; ++ap) {
        const float2 em = em_p[(size_t)ap * T_DIM];   // coalesced across t
        const float4 ei = eipv[ap];
        const float4 vv = v4[ap];
        // s-row 0
        float ea  = ei.x * em.x;
        float eb  = ei.y * em.y;
        float den = fmaf(ea, eb, (ea + eb) + 1.f);
        float num = fmaf(vv.x, eb, fmaf(vv.y, ea, vv.z));
        acc0 = fmaf(num, __builtin_amdgcn_rcpf(den), acc0);
        // s-row 1
        ea  = ei.z * em.x;
        eb  = ei.w * em.y;
        den = fmaf(ea, eb, (ea + eb) + 1.f);
        num = fmaf(vv.x, eb, fmaf(vv.y, ea, vv.z));
        acc1 = fmaf(num, __builtin_amdgcn_rcpf(den), acc1);
    }

    // v.tanh sum = sumV - 2*acc; constant sumV cancels in softmax.
    const bool valid = (mask[t * B_DIM + b] != 0);
    const float l0 = valid ? (-2.f * acc0) : NEG_INF_F;
    const float l1 = valid ? (-2.f * acc1) : NEG_INF_F;

    // ---- softmax over t, both s rows fused ----
    float m0 = warp_red_max(l0), m1 = warp_red_max(l1);
    if (lane == 0) { redm[0][wave] = m0; redm[1][wave] = m1; }
    __syncthreads();
    m0 = fmaxf(fmaxf(redm[0][0], redm[0][1]), fmaxf(redm[0][2], redm[0][3]));
    m1 = fmaxf(fmaxf(redm[1][0], redm[1][1]), fmaxf(redm[1][2], redm[1][3]));
    const float e0 = __expf(l0 - m0);
    const float e1 = __expf(l1 - m1);
    float su0 = warp_red_sum(e0), su1 = warp_red_sum(e1);
    __syncthreads();
    if (lane == 0) { redm[0][wave] = su0; redm[1][wave] = su1; }
    __syncthreads();
    su0 = (redm[0][0] + redm[0][1]) + (redm[0][2] + redm[0][3]);
    su1 = (redm[1][0] + redm[1][1]) + (redm[1][2] + redm[1][3]);
    sc[0][t] = e0 * __builtin_amdgcn_rcpf(su0);
    sc[1][t] = e1 * __builtin_amdgcn_rcpf(su1);
    __syncthreads();

    // ---- Phase 2: context. thread = (t-quarter tq, float4 column d4). ----
    const int d4 = tid & 63;          // float4 column: d = d4*4
    const int tq = wave;              // t-quarter = wave index (sc[.][t2] wave-uniform)
    float4 c0 = {0.f, 0.f, 0.f, 0.f}, c1 = {0.f, 0.f, 0.f, 0.f};
    const float4* in_b4 = (const float4*)(input + b * DIN) + d4;
    const int t_base = tq * 64;
    #pragma unroll 8
    for (int i = 0; i < 64; ++i) {
        const int t2 = t_base + i;
        const float4 xv = in_b4[(size_t)t2 * (B_DIM * DIN / 4)];  // 1KB/wave, coalesced
        const float s0v = sc[0][t2];   // wave-uniform broadcast
        const float s1v = sc[1][t2];
        c0.x = fmaf(s0v, xv.x, c0.x); c0.y = fmaf(s0v, xv.y, c0.y);
        c0.z = fmaf(s0v, xv.z, c0.z); c0.w = fmaf(s0v, xv.w, c0.w);
        c1.x = fmaf(s1v, xv.x, c1.x); c1.y = fmaf(s1v, xv.y, c1.y);
        c1.z = fmaf(s1v, xv.z, c1.z); c1.w = fmaf(s1v, xv.w, c1.w);
    }
    part[tq][0][d4] = c0;
    part[tq][1][d4] = c1;
    __syncthreads();

    if (tid < 128) {
        const int s = tid >> 6;       // 0 or 1
        const float4 p0 = part[0][s][d4];
        const float4 p1 = part[1][s][d4];
        const float4 p2 = part[2][s][d4];
        const float4 p3 = part[3][s][d4];
        float4 c;
        c.x = (p0.x + p1.x) + (p2.x + p3.x);
        c.y = (p0.y + p1.y) + (p2.y + p3.y);
        c.z = (p0.z + p1.z) + (p2.z + p3.z);
        c.w = (p0.w + p1.w) + (p2.w + p3.w);
        const int row = (s0 + s) * B_DIM + b;
        *((float4*)(out + (size_t)row * (2 * DIN)) + d4) = c;
        const float4 inrow = *((const float4*)(input + (size_t)row * DIN) + d4);
        *((float4*)(out + (size_t)row * (2 * DIN) + DIN) + d4) = inrow;
    }
}

extern "C" void kernel_launch(void* const* d_in, const int* in_sizes, int n_in,
                              void* d_out, int out_size, void* d_ws, size_t ws_size,
                              hipStream_t stream) {
    const float* input  = (const float*)d_in[0];
    const float* memory = (const float*)d_in[1];
    const int*   mask   = (const int*)d_in[2];
    const float* Wi     = (const float*)d_in[3];
    const float* Wm     = (const float*)d_in[4];
    const float* v      = (const float*)d_in[5];
    float* out = (float*)d_out;

    float* EIP = (float*)d_ws;                           // [T*B][A]        1 MB  exp2(ip)
    float* EM2 = EIP + (size_t)T_DIM * B_DIM * A_DIM;    // [B][A/2][T][2]  1 MB  exp2(mp) a-paired

    proj_kernel<<<(T_DIM * B_DIM) / PROJ_TT, 256, 0, stream>>>(input, memory, Wi, Wm, EIP, EM2);
    attn_kernel<<<(T_DIM / S_PAIR) * B_DIM, 256, 0, stream>>>(input, mask, v, EIP, EM2, out);
}

// Round 10
// 97.554 us; speedup vs baseline: 1.0466x; 1.0218x over previous
//
#include <hip/hip_runtime.h>

#define T_DIM 256
#define B_DIM 8
#define DIN   256
#define DM    256
#define A_DIM 128
#define AP_DIM (A_DIM / 2)   // a-pairs
#define NEG_INF_F (-1e30f)
// tanh(x) needs exp(2x); v_exp_f32 computes 2^y -> projections scaled by 2*log2(e),
// stored as exp2 factors (exp2(ip+mp) = exp2(ip)*exp2(mp)).
#define PRESCALE 2.885390081777927f
#define PROJ_TT 8   // (t,b) rows per proj block (512 threads)
#define S_TILE  4   // s rows per fused-attention block

// ---------------- Kernel A: projections -> EIP=exp2(ip) [row][a],
//                  EM2=exp2(mp) packed as [b][a/2][t][2] ----------------
// 512 threads: group = tid>>7 (0: IP rows 0-3, 1: IP rows 4-7,
//                              2: EM rows 0-3, 3: EM rows 4-7), a = tid&127.
// Both IP groups stream the same Wi lines (second wave L1-hits) -> W L2
// traffic = 256 KB/block * 256 blocks = 64 MB.
__global__ __launch_bounds__(512) void proj_kernel(
    const float* __restrict__ input, const float* __restrict__ memory,
    const float* __restrict__ Wi, const float* __restrict__ Wm,
    float* __restrict__ EIP, float* __restrict__ EM2)
{
    __shared__ float xin[PROJ_TT][DIN];
    __shared__ float xmem[PROJ_TT][DM];
    const int row0 = blockIdx.x * PROJ_TT;           // flat (t*B+b) row index
    const int tid  = threadIdx.x;

    for (int i = tid; i < PROJ_TT * DIN; i += 512) {
        const int r = i >> 8, d = i & 255;
        xin[r][d]  = input[(row0 + r) * DIN + d];
        xmem[r][d] = memory[(row0 + r) * DM + d];
    }
    __syncthreads();

    const int group = tid >> 7;
    const int a     = tid & 127;
    const int r0    = (group & 1) * 4;

    if (group < 2) {
        float acc[4] = {0.f, 0.f, 0.f, 0.f};
        #pragma unroll 8
        for (int d = 0; d < DIN; ++d) {
            const float w = Wi[d * A_DIM + a];
            #pragma unroll
            for (int r = 0; r < 4; ++r)
                acc[r] = fmaf(xin[r0 + r][d], w, acc[r]);
        }
        #pragma unroll
        for (int r = 0; r < 4; ++r)
            EIP[(row0 + r0 + r) * A_DIM + a] =
                __builtin_amdgcn_exp2f(acc[r] * PRESCALE);
    } else {
        float acc[4] = {0.f, 0.f, 0.f, 0.f};
        #pragma unroll 8
        for (int d = 0; d < DM; ++d) {
            const float w = Wm[d * A_DIM + a];
            #pragma unroll
            for (int r = 0; r < 4; ++r)
                acc[r] = fmaf(xmem[r0 + r][d], w, acc[r]);
        }
        #pragma unroll
        for (int r = 0; r < 4; ++r) {
            const int row = row0 + r0 + r;
            const int t = row / B_DIM, b = row % B_DIM;
            EM2[(((size_t)b * AP_DIM + (a >> 1)) * T_DIM + t) * 2 + (a & 1)] =
                __builtin_amdgcn_exp2f(acc[r] * PRESCALE);
        }
    }
}

__device__ inline float warp_red_max(float v) {
    #pragma unroll
    for (int o = 32; o > 0; o >>= 1) v = fmaxf(v, __shfl_xor(v, o, 64));
    return v;
}
__device__ inline float warp_red_sum(float v) {
    #pragma unroll
    for (int o = 32; o > 0; o >>= 1) v += __shfl_xor(v, o, 64);
    return v;
}

// ---------------- Kernel B: fused logits + softmax + context + concat ----------------
// block per (s-tile of 4, b): 512 blocks x 4 waves (2 blocks/CU).
// Phase 1: thread = key t, paired-rcp logits, 4 s-rows per EM load.
// Phase 2: thread = (t-quarter, float4 d-column); 4-way LDS reduction.
__global__ __launch_bounds__(256) void attn_kernel(
    const float* __restrict__ input, const int* __restrict__ mask,
    const float* __restrict__ v, const float* __restrict__ EIP,
    const float* __restrict__ EM2, float* __restrict__ out)
{
    __shared__ float4 eipv[2][AP_DIM];  // [sp][ap] = {e(2sp,a0), e(2sp,a1), e(2sp+1,a0), e(2sp+1,a1)}
    __shared__ float4 v4[AP_DIM];       // {va, vb, va+vb, 0}
    __shared__ float sc[S_TILE][T_DIM];
    __shared__ float redm[S_TILE][4];
    __shared__ float4 part[4][S_TILE][64];   // phase-2 partials, 16 KB

    const int blk = blockIdx.x;
    const int b   = blk % B_DIM;          // same-b neighbors -> L2 locality for EM/input
    const int s0  = (blk / B_DIM) * S_TILE;
    const int tid = threadIdx.x;
    const int lane = tid & 63;
    const int wave = tid >> 6;

    {
        float* eipf = (float*)eipv;
        float* v4f  = (float*)v4;
        if (tid < A_DIM) {
            const int a = tid, ap = a >> 1, j = a & 1;
            #pragma unroll
            for (int sp = 0; sp < 2; ++sp) {
                eipf[(sp * AP_DIM + ap) * 4 + j]     = EIP[((s0 + 2 * sp + 0) * B_DIM + b) * A_DIM + a];
                eipf[(sp * AP_DIM + ap) * 4 + 2 + j] = EIP[((s0 + 2 * sp + 1) * B_DIM + b) * A_DIM + a];
            }
            v4f[ap * 4 + j] = v[a];
        }
        if (tid < AP_DIM) {
            v4f[tid * 4 + 2] = v[2 * tid] + v[2 * tid + 1];
            v4f[tid * 4 + 3] = 0.f;
        }
    }
    __syncthreads();

    // ---- Phase 1: logits. thread = key t. Paired-rcp:
    //   v_a/(1+e_a)+v_b/(1+e_b) = [v_a e_b + v_b e_a + (v_a+v_b)] / [(1+e_a)(1+e_b)]
    const int t = tid;
    float acc[S_TILE] = {0.f, 0.f, 0.f, 0.f};
    const float2* em_p = (const float2*)EM2 + (size_t)b * AP_DIM * T_DIM + t;
    #pragma unroll 4
    for (int ap = 0; ap < AP_DIM; ++ap) {
        const float2 em = em_p[(size_t)ap * T_DIM];   // coalesced across t
        const float4 vv = v4[ap];
        #pragma unroll
        for (int sp = 0; sp < 2; ++sp) {
            const float4 ei = eipv[sp][ap];
            // s-row 2sp
            float ea  = ei.x * em.x;
            float eb  = ei.y * em.y;
            float den = fmaf(ea, eb, (ea + eb) + 1.f);
            float num = fmaf(vv.x, eb, fmaf(vv.y, ea, vv.z));
            acc[2 * sp + 0] = fmaf(num, __builtin_amdgcn_rcpf(den), acc[2 * sp + 0]);
            // s-row 2sp+1
            ea  = ei.z * em.x;
            eb  = ei.w * em.y;
            den = fmaf(ea, eb, (ea + eb) + 1.f);
            num = fmaf(vv.x, eb, fmaf(vv.y, ea, vv.z));
            acc[2 * sp + 1] = fmaf(num, __builtin_amdgcn_rcpf(den), acc[2 * sp + 1]);
        }
    }

    // v.tanh sum = sumV - 2*acc; constant sumV cancels in softmax.
    const bool valid = (mask[t * B_DIM + b] != 0);
    float l[S_TILE], ex[S_TILE], su[S_TILE];
    #pragma unroll
    for (int s = 0; s < S_TILE; ++s)
        l[s] = valid ? (-2.f * acc[s]) : NEG_INF_F;

    // ---- softmax over t, all 4 s rows fused ----
    #pragma unroll
    for (int s = 0; s < S_TILE; ++s) {
        const float m = warp_red_max(l[s]);
        if (lane == 0) redm[s][wave] = m;
    }
    __syncthreads();
    #pragma unroll
    for (int s = 0; s < S_TILE; ++s) {
        const float m = fmaxf(fmaxf(redm[s][0], redm[s][1]), fmaxf(redm[s][2], redm[s][3]));
        ex[s] = __expf(l[s] - m);
        su[s] = warp_red_sum(ex[s]);
    }
    __syncthreads();
    if (lane == 0) {
        #pragma unroll
        for (int s = 0; s < S_TILE; ++s) redm[s][wave] = su[s];
    }
    __syncthreads();
    #pragma unroll
    for (int s = 0; s < S_TILE; ++s) {
        const float sum = (redm[s][0] + redm[s][1]) + (redm[s][2] + redm[s][3]);
        sc[s][t] = ex[s] * __builtin_amdgcn_rcpf(sum);
    }
    __syncthreads();

    // ---- Phase 2: context. thread = (t-quarter tq, float4 column d4). ----
    const int d4 = lane;              // float4 column: d = d4*4
    const int tq = wave;              // t-quarter = wave index (sc[.][t2] wave-uniform)
    float4 c[S_TILE];
    #pragma unroll
    for (int s = 0; s < S_TILE; ++s) c[s] = {0.f, 0.f, 0.f, 0.f};
    const float4* in_b4 = (const float4*)(input + b * DIN) + d4;
    const int t_base = tq * 64;
    #pragma unroll 4
    for (int i = 0; i < 64; ++i) {
        const int t2 = t_base + i;
        const float4 xv = in_b4[(size_t)t2 * (B_DIM * DIN / 4)];  // 1KB/wave, coalesced
        #pragma unroll
        for (int s = 0; s < S_TILE; ++s) {
            const float sv = sc[s][t2];   // wave-uniform broadcast
            c[s].x = fmaf(sv, xv.x, c[s].x);
            c[s].y = fmaf(sv, xv.y, c[s].y);
            c[s].z = fmaf(sv, xv.z, c[s].z);
            c[s].w = fmaf(sv, xv.w, c[s].w);
        }
    }
    #pragma unroll
    for (int s = 0; s < S_TILE; ++s) part[tq][s][d4] = c[s];
    __syncthreads();

    {
        const int s = wave;           // 4 s-rows x 64 columns = 256 threads
        const float4 p0 = part[0][s][d4];
        const float4 p1 = part[1][s][d4];
        const float4 p2 = part[2][s][d4];
        const float4 p3 = part[3][s][d4];
        float4 cc;
        cc.x = (p0.x + p1.x) + (p2.x + p3.x);
        cc.y = (p0.y + p1.y) + (p2.y + p3.y);
        cc.z = (p0.z + p1.z) + (p2.z + p3.z);
        cc.w = (p0.w + p1.w) + (p2.w + p3.w);
        const int row = (s0 + s) * B_DIM + b;
        *((float4*)(out + (size_t)row * (2 * DIN)) + d4) = cc;
        const float4 inrow = *((const float4*)(input + (size_t)row * DIN) + d4);
        *((float4*)(out + (size_t)row * (2 * DIN) + DIN) + d4) = inrow;
    }
}

extern "C" void kernel_launch(void* const* d_in, const int* in_sizes, int n_in,
                              void* d_out, int out_size, void* d_ws, size_t ws_size,
                              hipStream_t stream) {
    const float* input  = (const float*)d_in[0];
    const float* memory = (const float*)d_in[1];
    const int*   mask   = (const int*)d_in[2];
    const float* Wi     = (const float*)d_in[3];
    const float* Wm     = (const float*)d_in[4];
    const float* v      = (const float*)d_in[5];
    float* out = (float*)d_out;

    float* EIP = (float*)d_ws;                           // [T*B][A]        1 MB  exp2(ip)
    float* EM2 = EIP + (size_t)T_DIM * B_DIM * A_DIM;    // [B][A/2][T][2]  1 MB  exp2(mp) a-paired

    proj_kernel<<<(T_DIM * B_DIM) / PROJ_TT, 512, 0, stream>>>(input, memory, Wi, Wm, EIP, EM2);
    attn_kernel<<<(T_DIM / S_TILE) * B_DIM, 256, 0, stream>>>(input, mask, v, EIP, EM2, out);
}